// Round 20
// baseline (895.245 us; speedup 1.0000x reference)
//
#include <hip/hip_runtime.h>

typedef float f32x4 __attribute__((ext_vector_type(4)));
typedef short short8 __attribute__((ext_vector_type(8)));

#define NWG_S 16   // serial-chain worker workgroups
#define AR 32      // a-rows per WG (512/16)
#define OR 25      // output rows per WG (400/16)

__device__ __forceinline__ unsigned short f2bf(float f) {
  unsigned int u = __float_as_uint(f);
  u += 0x7fffu + ((u >> 16) & 1u);
  return (unsigned short)(u >> 16);
}
#define DRAIN() asm volatile("s_waitcnt vmcnt(0)" ::: "memory")
#define ALOAD(p) __hip_atomic_load((p), __ATOMIC_RELAXED, __HIP_MEMORY_SCOPE_AGENT)
#define ASTORE(p, v) __hip_atomic_store((p), (v), __ATOMIC_RELAXED, __HIP_MEMORY_SCOPE_AGENT)
#define AFADD(p, v) __hip_atomic_fetch_add((p), (v), __ATOMIC_RELAXED, __HIP_MEMORY_SCOPE_AGENT)

// ---------------- workspace layout (bytes) ----------------
// 0       : w2t       bf16[128][576]  transposed conv2 weights (147456)
// 147456  : feats_sum f32 [128][128]  (65536)   zeroed each launch
// 212992  : ev        f32 [896]       (3584)
// 216576  : base      f32 [128][400]  (204800)
// 421376  : acc       f32 [4][400]    logit accumulators, 4-deep rotation (6400) zeroed
// 427776  : seq       int [1]         monotonic arrival counter, zeroed
// 524288  : c1        bf16[FCHUNK][128][128][64] (FCHUNK*2 MiB)

// ================= prep: zero accumulators, transpose conv2_w, fce branch ==
__global__ __launch_bounds__(256) void prep_k(
    const float* __restrict__ enc, const float* __restrict__ fce_w,
    const float* __restrict__ fce_b, const float* __restrict__ conv2_w,
    unsigned short* __restrict__ w2t, float* __restrict__ ev,
    float* __restrict__ feats_sum, float* __restrict__ acc,
    int* __restrict__ seq) {
  int b = blockIdx.x, t = threadIdx.x;
  if (b < 48) {
    for (int i = b * 256 + t; i < 17985; i += 48 * 256) {
      if (i < 16384) feats_sum[i] = 0.f;
      else if (i < 17984) acc[i - 16384] = 0.f;
      else seq[0] = 0;
    }
    for (int i = b * 256 + t; i < 73728; i += 48 * 256) {
      int oc = i / 576, k = i - oc * 576;
      int p = k >> 6, ic = k & 63;
      int ky = p / 3, kx = p - ky * 3;
      w2t[i] = f2bf(conv2_w[((oc * 64 + ic) * 3 + ky) * 3 + kx]);
    }
  } else {
    // ev[n*64+o] = relu(enc[n,:] . fce_w[o,:] + fce_b[o]); 16 blocks x 56 outs
    if (t < 224) {
      int o_l = t >> 2, part = t & 3;
      int o_glob = (b - 48) * 56 + o_l;
      int n = o_glob >> 6, o = o_glob & 63;
      const f32x4* e4 = (const f32x4*)(enc + n * 2048);
      const f32x4* w4 = (const f32x4*)(fce_w + o * 2048);
      float s = 0.f;
      for (int d = part * 128; d < part * 128 + 128; ++d) {
        f32x4 a = e4[d], w = w4[d];
        s += a.x * w.x + a.y * w.y + a.z * w.z + a.w * w.w;
      }
      s += __shfl_xor(s, 1);
      s += __shfl_xor(s, 2);
      if (part == 0) ev[o_glob] = fmaxf(s + fce_b[o], 0.f);
    }
  }
}

// ========== conv1: 2 px/thread, LDS-staged fully-coalesced c1 stores =======
// (R16-verified: kills the 4.5x write amplification.)
__global__ __launch_bounds__(256) void conv1_k(
    const float* __restrict__ vid, const float* __restrict__ cw,
    const float* __restrict__ cb, unsigned short* __restrict__ c1, int fbase) {
  __shared__ unsigned short sst[512 * 64];  // 64 KB staging
  int t = threadIdx.x;
  int f_local = blockIdx.x >> 5;
  int r = blockIdx.x & 31;
  int pix = r * 512 + t * 2;  // 0..16382, even
  int oy = pix >> 7, ox = pix & 127;  // ox even
  int f = fbase + f_local;
  float inv[45];
#pragma unroll
  for (int c = 0; c < 3; ++c)
#pragma unroll
    for (int ky = 0; ky < 3; ++ky) {
      int iy = 2 * oy - 1 + ky;
#pragma unroll
      for (int dx = 0; dx < 5; ++dx) {
        int ix = 2 * ox - 1 + dx;
        bool ok = (iy >= 0 && iy < 256 && ix >= 0 && ix < 256);
        inv[c * 15 + ky * 5 + dx] =
            ok ? vid[((f * 3 + c) * 256 + iy) * 256 + ix] : 0.f;
      }
    }
  uint4* st4 = (uint4*)sst;
  const int lp0 = 2 * t, sw = t & 7;
  for (int g = 0; g < 8; ++g) {
    unsigned short pk0[8], pk1[8];
#pragma unroll
    for (int j = 0; j < 8; ++j) {
      int oc = g * 8 + j;
      float s0 = cb[oc], s1 = s0;
#pragma unroll
      for (int c = 0; c < 3; ++c)
#pragma unroll
        for (int ky = 0; ky < 3; ++ky)
#pragma unroll
          for (int kx = 0; kx < 3; ++kx) {
            float w = cw[oc * 27 + c * 9 + ky * 3 + kx];
            s0 += w * inv[c * 15 + ky * 5 + kx];
            s1 += w * inv[c * 15 + ky * 5 + kx + 2];
          }
      pk0[j] = f2bf(fmaxf(s0, 0.f));
      pk1[j] = f2bf(fmaxf(s1, 0.f));
    }
    st4[lp0 * 8 + (g ^ sw)] = *(const uint4*)pk0;        // swizzled stage
    st4[(lp0 + 1) * 8 + (g ^ sw)] = *(const uint4*)pk1;
  }
  __syncthreads();
  // phase 2: linear coalesced stream of the 64 KB slab
  uint4* dst4 = (uint4*)(c1 + ((long)(f_local * 16384 + r * 512)) * 64);
#pragma unroll
  for (int i = 0; i < 16; ++i) {
    int idx = t + i * 256;
    int lp = idx >> 3, gl = idx & 7;
    dst4[idx] = st4[lp * 8 + (gl ^ ((lp >> 1) & 7))];
  }
}

// ============ conv2: MFMA implicit GEMM, T14 reg-staged + LDS dbuf =========
// (R12-verified.)
__global__ __launch_bounds__(256) void conv2_k(
    const unsigned short* __restrict__ c1, const unsigned short* __restrict__ w2t,
    const float* __restrict__ c2b, float* __restrict__ feats_sum, int fbase) {
  __shared__ unsigned short As[2][128 * 40];
  __shared__ unsigned short Bs[2][128 * 40];
  __shared__ float fred[128];
  int t = threadIdx.x;
  int f_local = blockIdx.x >> 5, mb = blockIdx.x & 31;
  int wave = t >> 6, lane = t & 63;

  f32x4 acc0[8], acc1[8];
#pragma unroll
  for (int n = 0; n < 8; ++n) {
    acc0[n] = (f32x4){0.f, 0.f, 0.f, 0.f};
    acc1[n] = (f32x4){0.f, 0.f, 0.f, 0.f};
  }

  int r = t >> 1, seg = t & 1;
  int m = mb * 128 + r;
  int oy = m >> 6, ox = m & 63;
  const int aoff = r * 40 + seg * 16;

  uint4 ra0, ra1, rb0, rb1;
#define LOADSTAGE(kk)                                                        \
  {                                                                          \
    int p_ = (kk) >> 1, ic0_ = ((kk)&1) * 32;                                \
    int ky_ = p_ / 3, kx_ = p_ - ky_ * 3;                                    \
    int iy_ = 2 * oy - 1 + ky_, ix_ = 2 * ox - 1 + kx_;                      \
    if (iy_ >= 0 && iy_ < 128 && ix_ >= 0 && ix_ < 128) {                    \
      const unsigned short* src_ =                                           \
          &c1[(long)((f_local * 128 + iy_) * 128 + ix_) * 64 + ic0_ +        \
              seg * 16];                                                     \
      ra0 = *(const uint4*)&src_[0];                                         \
      ra1 = *(const uint4*)&src_[8];                                         \
    } else {                                                                 \
      ra0 = make_uint4(0u, 0u, 0u, 0u);                                      \
      ra1 = make_uint4(0u, 0u, 0u, 0u);                                      \
    }                                                                        \
    const unsigned short* bsrc_ = &w2t[r * 576 + p_ * 64 + ic0_ + seg * 16]; \
    rb0 = *(const uint4*)&bsrc_[0];                                          \
    rb1 = *(const uint4*)&bsrc_[8];                                          \
  }
#define WRITESTAGE(buf)                    \
  {                                        \
    *(uint4*)&As[buf][aoff] = ra0;         \
    *(uint4*)&As[buf][aoff + 8] = ra1;     \
    *(uint4*)&Bs[buf][aoff] = rb0;         \
    *(uint4*)&Bs[buf][aoff + 8] = rb1;     \
  }

  LOADSTAGE(0);
  WRITESTAGE(0);
  __syncthreads();

  for (int kk = 0; kk < 18; ++kk) {
    int cur = kk & 1;
    if (kk < 17) LOADSTAGE(kk + 1);
    short8 av0 =
        *(const short8*)&As[cur][(wave * 32 + (lane & 15)) * 40 + (lane >> 4) * 8];
    short8 av1 = *(const short8*)&As[cur][(wave * 32 + 16 + (lane & 15)) * 40 +
                                          (lane >> 4) * 8];
#pragma unroll
    for (int n = 0; n < 8; ++n) {
      short8 bv =
          *(const short8*)&Bs[cur][(n * 16 + (lane & 15)) * 40 + (lane >> 4) * 8];
      acc0[n] = __builtin_amdgcn_mfma_f32_16x16x32_bf16(av0, bv, acc0[n], 0, 0, 0);
      acc1[n] = __builtin_amdgcn_mfma_f32_16x16x32_bf16(av1, bv, acc1[n], 0, 0, 0);
    }
    if (kk < 17) WRITESTAGE(cur ^ 1);
    __syncthreads();
  }

  if (t < 128) fred[t] = 0.f;
  __syncthreads();
  int f = fbase + f_local;
  int colLane = lane & 15;
#pragma unroll
  for (int n = 0; n < 8; ++n) {
    float bias = c2b[n * 16 + colLane];
    float s = 0.f;
#pragma unroll
    for (int q = 0; q < 4; ++q)
      s += fmaxf(acc0[n][q] + bias, 0.f) + fmaxf(acc1[n][q] + bias, 0.f);
    s += __shfl_xor(s, 16);
    s += __shfl_xor(s, 32);
    if (lane < 16) atomicAdd(&fred[n * 16 + colLane], s);
  }
  __syncthreads();
  if (t < 128) atomicAdd(&feats_sum[f * 128 + t], fred[t]);
}

// ====== base[t][c] = feats_t.Wf + ev.We + fc_b (time-independent part) =====
__global__ __launch_bounds__(256) void base_k(
    const float* __restrict__ feats_sum, const float* __restrict__ ev,
    const float* __restrict__ fc_w, const float* __restrict__ fc_b,
    float* __restrict__ base) {
  __shared__ float xv[1024];
  int tfr = blockIdx.x, t = threadIdx.x;
  for (int i = t; i < 1024; i += 256)
    xv[i] = (i < 128) ? feats_sum[tfr * 128 + i] * (1.f / 4096.f) : ev[i - 128];
  __syncthreads();
  for (int c = t; c < 400; c += 256) {
    const float* wr = fc_w + c * 1536;
    float s = fc_b[c];
    for (int k = 0; k < 1024; k += 4) {
      f32x4 w4 = *(const f32x4*)&wr[k];
      s += w4.x * xv[k] + w4.y * xv[k + 1] + w4.z * xv[k + 2] + w4.w * xv[k + 3];
    }
    base[tfr * 400 + c] = s;
  }
}

// ============ serial chain: atomic-accumulate exchange + monotonic counter =
// Phase B publishes partial logits via agent-scope f32 atomicAdd into
// acc[step&3][400]; arrival tracked by ONE monotonic counter (AFADD after
// the vmcnt drain). Readers poll seq[0] >= 16*(step+1) — single hot line,
// no reset. Owner-zeroing one step delayed: counter >= 16(s+1) certifies all
// WGs published s, hence finished combining s-1 -> zero buf[(s-1)&3] is safe
// and its stores drain before this WG's next publish. All agent-scope.
__global__ __launch_bounds__(256) void serial_k(
    const float* __restrict__ fca_w, const float* __restrict__ fca_b,
    const float* __restrict__ fc_w, const float* __restrict__ action,
    const float* __restrict__ base, float* __restrict__ acc,
    int* __restrict__ seq, float* __restrict__ out) {
  int g = blockIdx.x;   // 0..15
  int t = threadIdx.x;
  __shared__ float wa[AR * 400];    // fca_w rows [g*32,+32)             51.2 KB
  __shared__ float wb2[400 * 33];   // fc_w[:,1024+g*32 ..+32] pad 33    52.8 KB
  __shared__ float sh_p[400];       // current softmax vector (local copy)
  __shared__ float sh_a[AR];        // own a slice
  __shared__ float sred[4];

  // ---- one-time LDS weight staging ----
  for (int i = t; i < AR * 400; i += 256) wa[i] = fca_w[g * AR * 400 + i];
  for (int i = t; i < 400 * 32; i += 256) {
    int r = i >> 5, c = i & 31;
    wb2[r * 33 + c] = fc_w[r * 1536 + 1024 + g * AR + c];
  }
  for (int i = t; i < 400; i += 256) sh_p[i] = action[i];  // step-0 input (raw)
  float fab = fca_b[g * AR + (t >> 3)];
  const int row = t >> 3;       // 0..31
  const int p4 = (t & 7) * 4;
  const unsigned lo = g * OR;
  __syncthreads();

  for (int step = 0; step < 128; ++step) {
    {  // ---- phase A: sh_a[row] = relu(wa[row,:].sh_p + b) ----
      const float* wrow = &wa[row * 400];
      float s = 0.f;
#pragma unroll
      for (int k = 0; k < 12; ++k) {
        f32x4 w = *(const f32x4*)&wrow[p4 + 32 * k];
        f32x4 x = *(const f32x4*)&sh_p[p4 + 32 * k];
        s += w.x * x.x + w.y * x.y + w.z * x.z + w.w * x.w;
      }
      if ((t & 7) < 4) {  // tail cols 384..399
        f32x4 w = *(const f32x4*)&wrow[384 + p4];
        f32x4 x = *(const f32x4*)&sh_p[384 + p4];
        s += w.x * x.x + w.y * x.y + w.z * x.z + w.w * x.w;
      }
      s += __shfl_xor(s, 1);
      s += __shfl_xor(s, 2);
      s += __shfl_xor(s, 4);
      if ((t & 7) == 0) sh_a[row] = fmaxf(s + fab, 0.f);
    }
    // prefetch base row (immutable, cached; hidden under phase A)
    float breg0 = base[step * 400 + t];
    float breg1 = (t < 144) ? base[step * 400 + 256 + t] : 0.f;
    __syncthreads();

    // ---- phase B: partial logits -> agent atomicAdd into acc[step&3] ----
    float* ab = acc + (step & 3) * 400;
    for (int c = t; c < 400; c += 256) {
      float s = 0.f;
#pragma unroll
      for (int j = 0; j < 32; ++j) s += wb2[c * 33 + j] * sh_a[j];
      AFADD(&ab[c], s);
    }
    DRAIN();          // adds at the coherence point
    __syncthreads();  // all waves drained
    if (t == 0) AFADD(&seq[0], 1);  // monotonic arrival

    // ---- wait for all 16 publishers (single hot counter) ----
    if (t == 0) {
      while (ALOAD(&seq[0]) < 16 * (step + 1)) __builtin_amdgcn_s_sleep(1);
    }
    __syncthreads();
    __builtin_amdgcn_fence(__ATOMIC_ACQUIRE, "agent");  // flash-inv for fresh reads

    // ---- combine: logits = base + acc (already summed); softmax local ----
    float l0 = ab[t] + breg0;
    float e0 = __expf(l0), e1 = 0.f;
    if (t < 144) e1 = __expf(ab[256 + t] + breg1);
    float sp = e0 + e1;
    sp += __shfl_xor(sp, 1);
    sp += __shfl_xor(sp, 2);
    sp += __shfl_xor(sp, 4);
    sp += __shfl_xor(sp, 8);
    sp += __shfl_xor(sp, 16);
    sp += __shfl_xor(sp, 32);
    if ((t & 63) == 0) sred[t >> 6] = sp;
    __syncthreads();
    float S = sred[0] + sred[1] + sred[2] + sred[3];
    float q0 = e0 / S;
    sh_p[t] = q0;
    if ((unsigned)(t - lo) < (unsigned)OR) out[step * 400 + t] = q0;
    if (t < 144) {
      float q1 = e1 / S;
      sh_p[256 + t] = q1;
      if ((unsigned)(256 + t - lo) < (unsigned)OR) out[step * 400 + 256 + t] = q1;
    }
    // ---- zero the buffer consumed last step (owner slice, write-through) ----
    if (step >= 1 && t < OR)
      ASTORE(&acc[((step - 1) & 3) * 400 + lo + t], 0.f);
    __syncthreads();  // sh_p ready for next phase A
  }
}

extern "C" void kernel_launch(void* const* d_in, const int* in_sizes, int n_in,
                              void* d_out, int out_size, void* d_ws, size_t ws_size,
                              hipStream_t stream) {
  (void)in_sizes; (void)n_in; (void)out_size;
  const float* enc    = (const float*)d_in[0];
  const float* vid    = (const float*)d_in[1];
  const float* action = (const float*)d_in[2];
  const float* c1w    = (const float*)d_in[3];
  const float* c1b    = (const float*)d_in[4];
  const float* c2w    = (const float*)d_in[5];
  const float* c2b    = (const float*)d_in[6];
  const float* fce_w  = (const float*)d_in[7];
  const float* fce_b  = (const float*)d_in[8];
  const float* fca_w  = (const float*)d_in[9];
  const float* fca_b  = (const float*)d_in[10];
  const float* fc_w   = (const float*)d_in[11];
  const float* fc_b   = (const float*)d_in[12];
  // d_in[13..16] (wih/whh/bih/bhh): dead code — LSTM state never reaches the output.
  float* out = (float*)d_out;
  char* ws = (char*)d_ws;
  unsigned short* w2t = (unsigned short*)(ws + 0);
  float* feats_sum    = (float*)(ws + 147456);
  float* ev           = (float*)(ws + 212992);
  float* base         = (float*)(ws + 216576);
  float* acc          = (float*)(ws + 421376);  // f32[4][400]
  int*   seq          = (int*)(ws + 427776);    // int[1] monotonic
  unsigned short* c1  = (unsigned short*)(ws + 524288);

  // fchunk=16: c1 chunk = 32 MB -> stays L3-resident (conv2's 9x re-reads and
  // conv1's writes never round-trip to HBM). Guard still shrinks if ws small.
  int fchunk = 16;
  while (fchunk > 1 && 524288ull + (unsigned long long)fchunk * 2097152ull > ws_size)
    fchunk >>= 1;

  hipLaunchKernelGGL(prep_k, dim3(64), dim3(256), 0, stream,
                     enc, fce_w, fce_b, c2w, w2t, ev, feats_sum, acc, seq);
  for (int fb = 0; fb < 128; fb += fchunk) {
    hipLaunchKernelGGL(conv1_k, dim3(fchunk * 32), dim3(256), 0, stream,
                       vid, c1w, c1b, c1, fb);
    hipLaunchKernelGGL(conv2_k, dim3(fchunk * 32), dim3(256), 0, stream,
                       c1, w2t, c2b, feats_sum, fb);
  }
  hipLaunchKernelGGL(base_k, dim3(128), dim3(256), 0, stream,
                     feats_sum, ev, fc_w, fc_b, base);
  hipLaunchKernelGGL(serial_k, dim3(NWG_S), dim3(256), 0, stream,
                     fca_w, fca_b, fc_w, action, base, acc, seq, out);
}

// Round 21
// 864.519 us; speedup vs baseline: 1.0355x; 1.0355x over previous
//
#include <hip/hip_runtime.h>

typedef float f32x4 __attribute__((ext_vector_type(4)));
typedef short short8 __attribute__((ext_vector_type(8)));

#define NWG_S 16   // serial-chain worker workgroups
#define AR 32      // a-rows per WG (512/16)
#define OR 25      // output rows per WG (400/16)

__device__ __forceinline__ unsigned short f2bf(float f) {
  unsigned int u = __float_as_uint(f);
  u += 0x7fffu + ((u >> 16) & 1u);
  return (unsigned short)(u >> 16);
}
#define DRAIN() asm volatile("s_waitcnt vmcnt(0)" ::: "memory")
#define ALOAD(p) __hip_atomic_load((p), __ATOMIC_RELAXED, __HIP_MEMORY_SCOPE_AGENT)
#define ASTORE(p, v) __hip_atomic_store((p), (v), __ATOMIC_RELAXED, __HIP_MEMORY_SCOPE_AGENT)
#define AFADD(p, v) __hip_atomic_fetch_add((p), (v), __ATOMIC_RELAXED, __HIP_MEMORY_SCOPE_AGENT)

// ---------------- workspace layout (bytes) ----------------
// 0       : w2t       bf16[128][576]  transposed conv2 weights (147456)
// 147456  : feats_sum f32 [128][128]  (65536)   zeroed each launch
// 212992  : ev        f32 [896]       (3584)
// 216576  : base      f32 [128][400]  (204800)
// 421376  : acc       f32 [4][400]    logit accumulators, 4-deep rotation (6400) zeroed
// 427776  : seq       int [1]         monotonic arrival counter, zeroed
// 524288  : c1        bf16[FCHUNK][128][128][64] (FCHUNK*2 MiB)

// ================= prep: zero accumulators, transpose conv2_w, fce branch ==
__global__ __launch_bounds__(256) void prep_k(
    const float* __restrict__ enc, const float* __restrict__ fce_w,
    const float* __restrict__ fce_b, const float* __restrict__ conv2_w,
    unsigned short* __restrict__ w2t, float* __restrict__ ev,
    float* __restrict__ feats_sum, float* __restrict__ acc,
    int* __restrict__ seq) {
  int b = blockIdx.x, t = threadIdx.x;
  if (b < 48) {
    for (int i = b * 256 + t; i < 17985; i += 48 * 256) {
      if (i < 16384) feats_sum[i] = 0.f;
      else if (i < 17984) acc[i - 16384] = 0.f;
      else seq[0] = 0;
    }
    for (int i = b * 256 + t; i < 73728; i += 48 * 256) {
      int oc = i / 576, k = i - oc * 576;
      int p = k >> 6, ic = k & 63;
      int ky = p / 3, kx = p - ky * 3;
      w2t[i] = f2bf(conv2_w[((oc * 64 + ic) * 3 + ky) * 3 + kx]);
    }
  } else {
    // ev[n*64+o] = relu(enc[n,:] . fce_w[o,:] + fce_b[o]); 16 blocks x 56 outs
    if (t < 224) {
      int o_l = t >> 2, part = t & 3;
      int o_glob = (b - 48) * 56 + o_l;
      int n = o_glob >> 6, o = o_glob & 63;
      const f32x4* e4 = (const f32x4*)(enc + n * 2048);
      const f32x4* w4 = (const f32x4*)(fce_w + o * 2048);
      float s = 0.f;
      for (int d = part * 128; d < part * 128 + 128; ++d) {
        f32x4 a = e4[d], w = w4[d];
        s += a.x * w.x + a.y * w.y + a.z * w.z + a.w * w.w;
      }
      s += __shfl_xor(s, 1);
      s += __shfl_xor(s, 2);
      if (part == 0) ev[o_glob] = fmaxf(s + fce_b[o], 0.f);
    }
  }
}

// ========== conv1: 2 px/thread, LDS-staged fully-coalesced c1 stores =======
// (R16-verified: kills the 4.5x write amplification.)
__global__ __launch_bounds__(256) void conv1_k(
    const float* __restrict__ vid, const float* __restrict__ cw,
    const float* __restrict__ cb, unsigned short* __restrict__ c1, int fbase) {
  __shared__ unsigned short sst[512 * 64];  // 64 KB staging
  int t = threadIdx.x;
  int f_local = blockIdx.x >> 5;
  int r = blockIdx.x & 31;
  int pix = r * 512 + t * 2;  // 0..16382, even
  int oy = pix >> 7, ox = pix & 127;  // ox even
  int f = fbase + f_local;
  float inv[45];
#pragma unroll
  for (int c = 0; c < 3; ++c)
#pragma unroll
    for (int ky = 0; ky < 3; ++ky) {
      int iy = 2 * oy - 1 + ky;
#pragma unroll
      for (int dx = 0; dx < 5; ++dx) {
        int ix = 2 * ox - 1 + dx;
        bool ok = (iy >= 0 && iy < 256 && ix >= 0 && ix < 256);
        inv[c * 15 + ky * 5 + dx] =
            ok ? vid[((f * 3 + c) * 256 + iy) * 256 + ix] : 0.f;
      }
    }
  uint4* st4 = (uint4*)sst;
  const int lp0 = 2 * t, sw = t & 7;
  for (int g = 0; g < 8; ++g) {
    unsigned short pk0[8], pk1[8];
#pragma unroll
    for (int j = 0; j < 8; ++j) {
      int oc = g * 8 + j;
      float s0 = cb[oc], s1 = s0;
#pragma unroll
      for (int c = 0; c < 3; ++c)
#pragma unroll
        for (int ky = 0; ky < 3; ++ky)
#pragma unroll
          for (int kx = 0; kx < 3; ++kx) {
            float w = cw[oc * 27 + c * 9 + ky * 3 + kx];
            s0 += w * inv[c * 15 + ky * 5 + kx];
            s1 += w * inv[c * 15 + ky * 5 + kx + 2];
          }
      pk0[j] = f2bf(fmaxf(s0, 0.f));
      pk1[j] = f2bf(fmaxf(s1, 0.f));
    }
    st4[lp0 * 8 + (g ^ sw)] = *(const uint4*)pk0;        // swizzled stage
    st4[(lp0 + 1) * 8 + (g ^ sw)] = *(const uint4*)pk1;
  }
  __syncthreads();
  // phase 2: linear coalesced stream of the 64 KB slab
  uint4* dst4 = (uint4*)(c1 + ((long)(f_local * 16384 + r * 512)) * 64);
#pragma unroll
  for (int i = 0; i < 16; ++i) {
    int idx = t + i * 256;
    int lp = idx >> 3, gl = idx & 7;
    dst4[idx] = st4[lp * 8 + (gl ^ ((lp >> 1) & 7))];
  }
}

// ============ conv2: MFMA implicit GEMM, T14 reg-staged + LDS dbuf =========
// (R12-verified.)
__global__ __launch_bounds__(256) void conv2_k(
    const unsigned short* __restrict__ c1, const unsigned short* __restrict__ w2t,
    const float* __restrict__ c2b, float* __restrict__ feats_sum, int fbase) {
  __shared__ unsigned short As[2][128 * 40];
  __shared__ unsigned short Bs[2][128 * 40];
  __shared__ float fred[128];
  int t = threadIdx.x;
  int f_local = blockIdx.x >> 5, mb = blockIdx.x & 31;
  int wave = t >> 6, lane = t & 63;

  f32x4 acc0[8], acc1[8];
#pragma unroll
  for (int n = 0; n < 8; ++n) {
    acc0[n] = (f32x4){0.f, 0.f, 0.f, 0.f};
    acc1[n] = (f32x4){0.f, 0.f, 0.f, 0.f};
  }

  int r = t >> 1, seg = t & 1;
  int m = mb * 128 + r;
  int oy = m >> 6, ox = m & 63;
  const int aoff = r * 40 + seg * 16;

  uint4 ra0, ra1, rb0, rb1;
#define LOADSTAGE(kk)                                                        \
  {                                                                          \
    int p_ = (kk) >> 1, ic0_ = ((kk)&1) * 32;                                \
    int ky_ = p_ / 3, kx_ = p_ - ky_ * 3;                                    \
    int iy_ = 2 * oy - 1 + ky_, ix_ = 2 * ox - 1 + kx_;                      \
    if (iy_ >= 0 && iy_ < 128 && ix_ >= 0 && ix_ < 128) {                    \
      const unsigned short* src_ =                                           \
          &c1[(long)((f_local * 128 + iy_) * 128 + ix_) * 64 + ic0_ +        \
              seg * 16];                                                     \
      ra0 = *(const uint4*)&src_[0];                                         \
      ra1 = *(const uint4*)&src_[8];                                         \
    } else {                                                                 \
      ra0 = make_uint4(0u, 0u, 0u, 0u);                                      \
      ra1 = make_uint4(0u, 0u, 0u, 0u);                                      \
    }                                                                        \
    const unsigned short* bsrc_ = &w2t[r * 576 + p_ * 64 + ic0_ + seg * 16]; \
    rb0 = *(const uint4*)&bsrc_[0];                                          \
    rb1 = *(const uint4*)&bsrc_[8];                                          \
  }
#define WRITESTAGE(buf)                    \
  {                                        \
    *(uint4*)&As[buf][aoff] = ra0;         \
    *(uint4*)&As[buf][aoff + 8] = ra1;     \
    *(uint4*)&Bs[buf][aoff] = rb0;         \
    *(uint4*)&Bs[buf][aoff + 8] = rb1;     \
  }

  LOADSTAGE(0);
  WRITESTAGE(0);
  __syncthreads();

  for (int kk = 0; kk < 18; ++kk) {
    int cur = kk & 1;
    if (kk < 17) LOADSTAGE(kk + 1);
    short8 av0 =
        *(const short8*)&As[cur][(wave * 32 + (lane & 15)) * 40 + (lane >> 4) * 8];
    short8 av1 = *(const short8*)&As[cur][(wave * 32 + 16 + (lane & 15)) * 40 +
                                          (lane >> 4) * 8];
#pragma unroll
    for (int n = 0; n < 8; ++n) {
      short8 bv =
          *(const short8*)&Bs[cur][(n * 16 + (lane & 15)) * 40 + (lane >> 4) * 8];
      acc0[n] = __builtin_amdgcn_mfma_f32_16x16x32_bf16(av0, bv, acc0[n], 0, 0, 0);
      acc1[n] = __builtin_amdgcn_mfma_f32_16x16x32_bf16(av1, bv, acc1[n], 0, 0, 0);
    }
    if (kk < 17) WRITESTAGE(cur ^ 1);
    __syncthreads();
  }

  if (t < 128) fred[t] = 0.f;
  __syncthreads();
  int f = fbase + f_local;
  int colLane = lane & 15;
#pragma unroll
  for (int n = 0; n < 8; ++n) {
    float bias = c2b[n * 16 + colLane];
    float s = 0.f;
#pragma unroll
    for (int q = 0; q < 4; ++q)
      s += fmaxf(acc0[n][q] + bias, 0.f) + fmaxf(acc1[n][q] + bias, 0.f);
    s += __shfl_xor(s, 16);
    s += __shfl_xor(s, 32);
    if (lane < 16) atomicAdd(&fred[n * 16 + colLane], s);
  }
  __syncthreads();
  if (t < 128) atomicAdd(&feats_sum[f * 128 + t], fred[t]);
}

// ====== base[t][c] = feats_t.Wf + ev.We + fc_b (time-independent part) =====
__global__ __launch_bounds__(256) void base_k(
    const float* __restrict__ feats_sum, const float* __restrict__ ev,
    const float* __restrict__ fc_w, const float* __restrict__ fc_b,
    float* __restrict__ base) {
  __shared__ float xv[1024];
  int tfr = blockIdx.x, t = threadIdx.x;
  for (int i = t; i < 1024; i += 256)
    xv[i] = (i < 128) ? feats_sum[tfr * 128 + i] * (1.f / 4096.f) : ev[i - 128];
  __syncthreads();
  for (int c = t; c < 400; c += 256) {
    const float* wr = fc_w + c * 1536;
    float s = fc_b[c];
    for (int k = 0; k < 1024; k += 4) {
      f32x4 w4 = *(const f32x4*)&wr[k];
      s += w4.x * xv[k] + w4.y * xv[k + 1] + w4.z * xv[k + 2] + w4.w * xv[k + 3];
    }
    base[tfr * 400 + c] = s;
  }
}

// ============ serial chain: atomic-accumulate exchange + monotonic counter =
// (R20-verified: 466 us.) Phase B publishes partial logits via agent-scope
// f32 atomicAdd into acc[step&3][400]; arrival tracked by ONE monotonic
// counter; owner-zeroing one step delayed. All agent-scope (R5/R17 lesson).
__global__ __launch_bounds__(256) void serial_k(
    const float* __restrict__ fca_w, const float* __restrict__ fca_b,
    const float* __restrict__ fc_w, const float* __restrict__ action,
    const float* __restrict__ base, float* __restrict__ acc,
    int* __restrict__ seq, float* __restrict__ out) {
  int g = blockIdx.x;   // 0..15
  int t = threadIdx.x;
  __shared__ float wa[AR * 400];    // fca_w rows [g*32,+32)             51.2 KB
  __shared__ float wb2[400 * 33];   // fc_w[:,1024+g*32 ..+32] pad 33    52.8 KB
  __shared__ float sh_p[400];       // current softmax vector (local copy)
  __shared__ float sh_a[AR];        // own a slice
  __shared__ float sred[4];

  // ---- one-time LDS weight staging ----
  for (int i = t; i < AR * 400; i += 256) wa[i] = fca_w[g * AR * 400 + i];
  for (int i = t; i < 400 * 32; i += 256) {
    int r = i >> 5, c = i & 31;
    wb2[r * 33 + c] = fc_w[r * 1536 + 1024 + g * AR + c];
  }
  for (int i = t; i < 400; i += 256) sh_p[i] = action[i];  // step-0 input (raw)
  float fab = fca_b[g * AR + (t >> 3)];
  const int row = t >> 3;       // 0..31
  const int p4 = (t & 7) * 4;
  const unsigned lo = g * OR;
  __syncthreads();

  for (int step = 0; step < 128; ++step) {
    {  // ---- phase A: sh_a[row] = relu(wa[row,:].sh_p + b) ----
      const float* wrow = &wa[row * 400];
      float s = 0.f;
#pragma unroll
      for (int k = 0; k < 12; ++k) {
        f32x4 w = *(const f32x4*)&wrow[p4 + 32 * k];
        f32x4 x = *(const f32x4*)&sh_p[p4 + 32 * k];
        s += w.x * x.x + w.y * x.y + w.z * x.z + w.w * x.w;
      }
      if ((t & 7) < 4) {  // tail cols 384..399
        f32x4 w = *(const f32x4*)&wrow[384 + p4];
        f32x4 x = *(const f32x4*)&sh_p[384 + p4];
        s += w.x * x.x + w.y * x.y + w.z * x.z + w.w * x.w;
      }
      s += __shfl_xor(s, 1);
      s += __shfl_xor(s, 2);
      s += __shfl_xor(s, 4);
      if ((t & 7) == 0) sh_a[row] = fmaxf(s + fab, 0.f);
    }
    // prefetch base row (immutable, cached; hidden under phase A)
    float breg0 = base[step * 400 + t];
    float breg1 = (t < 144) ? base[step * 400 + 256 + t] : 0.f;
    __syncthreads();

    // ---- phase B: partial logits -> agent atomicAdd into acc[step&3] ----
    float* ab = acc + (step & 3) * 400;
    for (int c = t; c < 400; c += 256) {
      float s = 0.f;
#pragma unroll
      for (int j = 0; j < 32; ++j) s += wb2[c * 33 + j] * sh_a[j];
      AFADD(&ab[c], s);
    }
    DRAIN();          // adds at the coherence point
    __syncthreads();  // all waves drained
    if (t == 0) AFADD(&seq[0], 1);  // monotonic arrival

    // ---- wait for all 16 publishers (single hot counter) ----
    if (t == 0) {
      while (ALOAD(&seq[0]) < 16 * (step + 1)) __builtin_amdgcn_s_sleep(1);
    }
    __syncthreads();
    __builtin_amdgcn_fence(__ATOMIC_ACQUIRE, "agent");  // flash-inv for fresh reads

    // ---- combine: logits = base + acc (already summed); softmax local ----
    float l0 = ab[t] + breg0;
    float e0 = __expf(l0), e1 = 0.f;
    if (t < 144) e1 = __expf(ab[256 + t] + breg1);
    float sp = e0 + e1;
    sp += __shfl_xor(sp, 1);
    sp += __shfl_xor(sp, 2);
    sp += __shfl_xor(sp, 4);
    sp += __shfl_xor(sp, 8);
    sp += __shfl_xor(sp, 16);
    sp += __shfl_xor(sp, 32);
    if ((t & 63) == 0) sred[t >> 6] = sp;
    __syncthreads();
    float S = sred[0] + sred[1] + sred[2] + sred[3];
    float q0 = e0 / S;
    sh_p[t] = q0;
    if ((unsigned)(t - lo) < (unsigned)OR) out[step * 400 + t] = q0;
    if (t < 144) {
      float q1 = e1 / S;
      sh_p[256 + t] = q1;
      if ((unsigned)(256 + t - lo) < (unsigned)OR) out[step * 400 + 256 + t] = q1;
    }
    // ---- zero the buffer consumed last step (owner slice, write-through) ----
    if (step >= 1 && t < OR)
      ASTORE(&acc[((step - 1) & 3) * 400 + lo + t], 0.f);
    __syncthreads();  // sh_p ready for next phase A
  }
}

extern "C" void kernel_launch(void* const* d_in, const int* in_sizes, int n_in,
                              void* d_out, int out_size, void* d_ws, size_t ws_size,
                              hipStream_t stream) {
  (void)in_sizes; (void)n_in; (void)out_size;
  const float* enc    = (const float*)d_in[0];
  const float* vid    = (const float*)d_in[1];
  const float* action = (const float*)d_in[2];
  const float* c1w    = (const float*)d_in[3];
  const float* c1b    = (const float*)d_in[4];
  const float* c2w    = (const float*)d_in[5];
  const float* c2b    = (const float*)d_in[6];
  const float* fce_w  = (const float*)d_in[7];
  const float* fce_b  = (const float*)d_in[8];
  const float* fca_w  = (const float*)d_in[9];
  const float* fca_b  = (const float*)d_in[10];
  const float* fc_w   = (const float*)d_in[11];
  const float* fc_b   = (const float*)d_in[12];
  // d_in[13..16] (wih/whh/bih/bhh): dead code — LSTM state never reaches the output.
  float* out = (float*)d_out;
  char* ws = (char*)d_ws;
  unsigned short* w2t = (unsigned short*)(ws + 0);
  float* feats_sum    = (float*)(ws + 147456);
  float* ev           = (float*)(ws + 212992);
  float* base         = (float*)(ws + 216576);
  float* acc          = (float*)(ws + 421376);  // f32[4][400]
  int*   seq          = (int*)(ws + 427776);    // int[1] monotonic
  unsigned short* c1  = (unsigned short*)(ws + 524288);

  // fchunk=128 (R19-verified best): single conv1/conv2 dispatch when ws allows
  int fchunk = 128;
  while (fchunk > 1 && 524288ull + (unsigned long long)fchunk * 2097152ull > ws_size)
    fchunk >>= 1;

  hipLaunchKernelGGL(prep_k, dim3(64), dim3(256), 0, stream,
                     enc, fce_w, fce_b, c2w, w2t, ev, feats_sum, acc, seq);
  for (int fb = 0; fb < 128; fb += fchunk) {
    hipLaunchKernelGGL(conv1_k, dim3(fchunk * 32), dim3(256), 0, stream,
                       vid, c1w, c1b, c1, fb);
    hipLaunchKernelGGL(conv2_k, dim3(fchunk * 32), dim3(256), 0, stream,
                       c1, w2t, c2b, feats_sum, fb);
  }
  hipLaunchKernelGGL(base_k, dim3(128), dim3(256), 0, stream,
                     feats_sum, ev, fc_w, fc_b, base);
  hipLaunchKernelGGL(serial_k, dim3(NWG_S), dim3(256), 0, stream,
                     fca_w, fca_b, fc_w, action, base, acc, seq, out);
}